// Round 9
// baseline (390.787 us; speedup 1.0000x reference)
//
#include <hip/hip_runtime.h>
#include <math.h>

#define N_NODES 50000
#define N_EDGES 800000
#define CAP 64                 // fixed CSR capacity/node (deg~Poisson(16))
#define RANGES 8
#define NODES_PER_RANGE 6250   // 50000 / 8
#define CSRB 1024              // csr blocks inside mix kernel
#define GEMMB 782              // ceil(50000/64)
#define LROW 136               // LDS row stride in shorts (272 B)

typedef __attribute__((ext_vector_type(8))) short short8;   // 8 bf16
typedef __attribute__((ext_vector_type(2))) short short2v;  // 2 bf16 packed
typedef __attribute__((ext_vector_type(4))) float f32x4;    // 4 fp32 acc

// ---------------- bf16 helpers (RNE) ----------------
__device__ __forceinline__ unsigned short f2bf(float f) {
    unsigned int u = __float_as_uint(f);
    return (unsigned short)((u + 0x7FFFu + ((u >> 16) & 1u)) >> 16);
}

// A fragment load: row-major fp32 (inline convert) or bf16.
template <bool F32>
__device__ __forceinline__ short8 loadA(const void* A, int off) {
    short8 r;
    if (F32) {
        const float* p = (const float*)A + off;   // 32B aligned
        float4 f0 = *(const float4*)p;
        float4 f1 = *(const float4*)(p + 4);
        r[0] = (short)f2bf(f0.x); r[1] = (short)f2bf(f0.y);
        r[2] = (short)f2bf(f0.z); r[3] = (short)f2bf(f0.w);
        r[4] = (short)f2bf(f1.x); r[5] = (short)f2bf(f1.y);
        r[6] = (short)f2bf(f1.z); r[7] = (short)f2bf(f1.w);
    } else {
        r = *(const short8*)((const unsigned short*)A + off);
    }
    return r;
}

// ---------------------------------------------------------------------------
// prep: pack 9 weight matrices fp32 -> bf16 fragment layout; zero deg.
// Bp[((c*N + n)*4 + q)*8 + j] = W[(c*32 + q*8 + j)*N + n].
// ---------------------------------------------------------------------------
struct WDescs { const float* W[9]; int N[9]; };

__global__ __launch_bounds__(256) void prep_kernel(
    WDescs wd, unsigned short* __restrict__ Wpk, int* __restrict__ deg)
{
    const int nthr = gridDim.x * 256;
    const int tid = blockIdx.x * 256 + threadIdx.x;
    for (int id = tid; id < 9 * 16384; id += nthr) {
        int mi = id >> 14;
        int loc = id & 16383;
        int N = wd.N[mi];
        if (loc < 128 * N) {
            int c = loc / (N * 32);
            int n = (loc - c * N * 32) >> 5;
            int k = c * 32 + (loc & 31);
            Wpk[mi * 16384 + loc] = f2bf(wd.W[mi][k * N + n]);
        }
    }
    for (int i = tid; i < N_NODES; i += nthr) deg[i] = 0;
}

// ---------------------------------------------------------------------------
// mix: blocks [0,CSRB) build CSR (XCD-range-partitioned, fixed capacity);
// blocks [CSRB, CSRB+GEMMB) compute Y1 = relu(x @ Wp1 + bp1) (bf16 out).
// Independent work -> no intra-kernel ordering needed.
// ---------------------------------------------------------------------------
__global__ __launch_bounds__(256) void mix_kernel(
    const int* __restrict__ esrc, const int* __restrict__ edst,
    int* __restrict__ deg, unsigned short* __restrict__ csr16,
    const float* __restrict__ x, const unsigned short* __restrict__ Wp1,
    const float* __restrict__ bp1, unsigned short* __restrict__ Y)
{
    if (blockIdx.x < CSRB) {
        int range = blockIdx.x & (RANGES - 1);
        for (int cb = blockIdx.x >> 3; cb < N_EDGES / 256; cb += CSRB / 8) {
            int e = cb * 256 + threadIdx.x;
            int d = edst[e];
            if ((unsigned)(d - range * NODES_PER_RANGE) < (unsigned)NODES_PER_RANGE) {
                int r = atomicAdd(&deg[d], 1);
                if (r < CAP) csr16[(d << 6) + r] = (unsigned short)esrc[e];
            }
        }
        return;
    }
    // ---- gemm1 layer 1: A = x fp32 ----
    const int tile = blockIdx.x - CSRB;
    const int lane = threadIdx.x & 63;
    const int wv = threadIdx.x >> 6;
    const int cl = lane & 15;
    const int quad = lane >> 4;
    const int rowBase = tile * 64 + wv * 16;
    const int ar = min(rowBase + cl, N_NODES - 1);
    const int bLane = cl * 32 + quad * 8;

    f32x4 acc[8];
    #pragma unroll
    for (int t = 0; t < 8; ++t) acc[t] = (f32x4){0.f, 0.f, 0.f, 0.f};

    #pragma unroll
    for (int c = 0; c < 4; ++c) {
        short8 af = loadA<true>(x, ar * 128 + c * 32 + quad * 8);
        const unsigned short* Bc = Wp1 + c * 4096 + bLane;
        #pragma unroll
        for (int t = 0; t < 8; ++t) {
            short8 bf = *(const short8*)(Bc + t * 512);
            acc[t] = __builtin_amdgcn_mfma_f32_16x16x32_bf16(af, bf, acc[t], 0, 0, 0);
        }
    }
    const int row0 = rowBase + quad * 4;
    #pragma unroll
    for (int t = 0; t < 8; ++t) {
        float bc = bp1[t * 16 + cl];
        #pragma unroll
        for (int g = 0; g < 4; ++g) {
            int r = row0 + g;
            if (r < N_NODES)
                Y[r * 128 + t * 16 + cl] = f2bf(fmaxf(acc[t][g] + bc, 0.0f));
        }
    }
}

// ---------------------------------------------------------------------------
// pd: fused pool + dual-GEMM + l2norm + (next-layer y-GEMM | fp32 out).
// Wave w pools its own 16 nodes from Yin into its private LDS region
// (row stride 272 B), then dual-GEMM reads the pool A-fragments from LDS.
// Epilogue stages h through the same LDS region for the y-GEMM. No
// __syncthreads needed: every LDS row is written and read by the same wave,
// and DS ops are in-order per wave.
//   A0F32: A-seg0 is fp32 (layer 1, A0 = x) else bf16.
//   LAST:  N=64, fp32 out, no y-GEMM.
// ---------------------------------------------------------------------------
template <bool A0F32, bool LAST>
__global__ __launch_bounds__(256) void pd_kernel(
    const void* __restrict__ A0,
    const unsigned short* __restrict__ B0, const unsigned short* __restrict__ B1,
    const float* __restrict__ bias,
    const unsigned short* __restrict__ Yin, const int* __restrict__ deg,
    const unsigned short* __restrict__ csr16,
    unsigned short* __restrict__ outH, float* __restrict__ outF,
    const unsigned short* __restrict__ Bnext, const float* __restrict__ bnext,
    unsigned short* __restrict__ Yout)
{
    constexpr int NT = LAST ? 4 : 8;
    constexpr int N = NT * 16;
    __shared__ unsigned short lds[4][16 * LROW];   // 17.4 KB

    const int lane = threadIdx.x & 63;
    const int wv = threadIdx.x >> 6;
    const int cl = lane & 15;
    const int quad = lane >> 4;
    const int tile = blockIdx.x;
    const int nodeBase = tile * 64 + wv * 16;
    unsigned short* plw = &lds[wv][0];

    // ---- pool 16 nodes into LDS (lane d handles dims {2d, 2d+1}) ----
    {
        const unsigned short* yb = Yin + 2 * lane;
        for (int j = 0; j < 16; ++j) {
            int n = min(nodeBase + j, N_NODES - 1);
            int e0 = n << 6;
            int e1 = e0 + min(deg[n], CAP);
            short2v acc = (short2v){0, 0};
            int e = e0;
            for (; e + 8 <= e1; e += 8) {
                int s0 = csr16[e + 0], s1 = csr16[e + 1];
                int s2 = csr16[e + 2], s3 = csr16[e + 3];
                int s4 = csr16[e + 4], s5 = csr16[e + 5];
                int s6 = csr16[e + 6], s7 = csr16[e + 7];
                short2v v0 = *(const short2v*)(yb + (s0 << 7));
                short2v v1 = *(const short2v*)(yb + (s1 << 7));
                short2v v2 = *(const short2v*)(yb + (s2 << 7));
                short2v v3 = *(const short2v*)(yb + (s3 << 7));
                short2v v4 = *(const short2v*)(yb + (s4 << 7));
                short2v v5 = *(const short2v*)(yb + (s5 << 7));
                short2v v6 = *(const short2v*)(yb + (s6 << 7));
                short2v v7 = *(const short2v*)(yb + (s7 << 7));
                acc = __builtin_elementwise_max(acc, v0);
                acc = __builtin_elementwise_max(acc, v1);
                acc = __builtin_elementwise_max(acc, v2);
                acc = __builtin_elementwise_max(acc, v3);
                acc = __builtin_elementwise_max(acc, v4);
                acc = __builtin_elementwise_max(acc, v5);
                acc = __builtin_elementwise_max(acc, v6);
                acc = __builtin_elementwise_max(acc, v7);
            }
            for (; e < e1; ++e) {
                int s = csr16[e];
                short2v v = *(const short2v*)(yb + (s << 7));
                acc = __builtin_elementwise_max(acc, v);
            }
            *(short2v*)(plw + j * LROW + 2 * lane) = acc;
        }
    }

    // ---- dual GEMM: acc = A0 @ B0 + PL @ B1 ----
    const int ar = min(nodeBase + cl, N_NODES - 1);
    const int bLane = cl * 32 + quad * 8;
    f32x4 acc[NT];
    #pragma unroll
    for (int t = 0; t < NT; ++t) acc[t] = (f32x4){0.f, 0.f, 0.f, 0.f};

    #pragma unroll
    for (int c = 0; c < 4; ++c) {
        short8 a0 = loadA<A0F32>(A0, ar * 128 + c * 32 + quad * 8);
        short8 a1 = *(const short8*)(plw + cl * LROW + c * 32 + quad * 8);
        const unsigned short* B0c = B0 + c * (N * 32) + bLane;
        const unsigned short* B1c = B1 + c * (N * 32) + bLane;
        #pragma unroll
        for (int t = 0; t < NT; ++t) {
            short8 bf = *(const short8*)(B0c + t * 512);
            acc[t] = __builtin_amdgcn_mfma_f32_16x16x32_bf16(a0, bf, acc[t], 0, 0, 0);
        }
        #pragma unroll
        for (int t = 0; t < NT; ++t) {
            short8 bf = *(const short8*)(B1c + t * 512);
            acc[t] = __builtin_amdgcn_mfma_f32_16x16x32_bf16(a1, bf, acc[t], 0, 0, 0);
        }
    }

    #pragma unroll
    for (int t = 0; t < NT; ++t) {
        float bc = bias[t * 16 + cl];
        #pragma unroll
        for (int g = 0; g < 4; ++g) acc[t][g] += bc;
    }

    // ---- fused row-wise L2 norm (row lives in 16 lanes of this quad group) ----
    float inv[4];
    #pragma unroll
    for (int g = 0; g < 4; ++g) {
        float s = 0.f;
        #pragma unroll
        for (int t = 0; t < NT; ++t) s += acc[t][g] * acc[t][g];
        s += __shfl_xor(s, 1, 64);
        s += __shfl_xor(s, 2, 64);
        s += __shfl_xor(s, 4, 64);
        s += __shfl_xor(s, 8, 64);
        inv[g] = 1.0f / fmaxf(sqrtf(s), 1e-12f);
    }

    const int row0 = nodeBase + quad * 4;

    if (LAST) {
        #pragma unroll
        for (int t = 0; t < NT; ++t)
            #pragma unroll
            for (int g = 0; g < 4; ++g) {
                int r = row0 + g;
                if (r < N_NODES)
                    outF[r * N + t * 16 + cl] = fmaxf(acc[t][g] * inv[g], 0.0f);
            }
        return;
    }

    // h -> global (next pd's A0) + LDS stage (C-layout -> A-layout round trip)
    #pragma unroll
    for (int t = 0; t < NT; ++t)
        #pragma unroll
        for (int g = 0; g < 4; ++g) {
            int r = row0 + g;
            unsigned short h = f2bf(fmaxf(acc[t][g] * inv[g], 0.0f));
            if (r < N_NODES) outH[r * 128 + t * 16 + cl] = h;
            plw[(quad * 4 + g) * LROW + t * 16 + cl] = h;
        }

    // ---- y-GEMM for the next layer: Yout = relu(h @ Bnext + bnext) ----
    f32x4 ya[8];
    #pragma unroll
    for (int t = 0; t < 8; ++t) ya[t] = (f32x4){0.f, 0.f, 0.f, 0.f};
    #pragma unroll
    for (int c = 0; c < 4; ++c) {
        short8 af = *(const short8*)(plw + cl * LROW + c * 32 + quad * 8);
        const unsigned short* Bc = Bnext + c * 4096 + bLane;
        #pragma unroll
        for (int t = 0; t < 8; ++t) {
            short8 bf = *(const short8*)(Bc + t * 512);
            ya[t] = __builtin_amdgcn_mfma_f32_16x16x32_bf16(af, bf, ya[t], 0, 0, 0);
        }
    }
    #pragma unroll
    for (int t = 0; t < 8; ++t) {
        float bc = bnext[t * 16 + cl];
        #pragma unroll
        for (int g = 0; g < 4; ++g) {
            int r = row0 + g;
            if (r < N_NODES)
                Yout[r * 128 + t * 16 + cl] = f2bf(fmaxf(ya[t][g] + bc, 0.0f));
        }
    }
}

extern "C" void kernel_launch(void* const* d_in, const int* in_sizes, int n_in,
                              void* d_out, int out_size, void* d_ws, size_t ws_size,
                              hipStream_t stream) {
    const float* x    = (const float*)d_in[0];
    const int*   esrc = (const int*)d_in[1];
    const int*   edst = (const int*)d_in[2];
    const float* Wp[3], *bp[3], *Ws[3], *Wn[3], *bb[3];
    for (int l = 0; l < 3; ++l) {
        Wp[l] = (const float*)d_in[3 + 5 * l];
        bp[l] = (const float*)d_in[4 + 5 * l];
        Ws[l] = (const float*)d_in[5 + 5 * l];
        Wn[l] = (const float*)d_in[6 + 5 * l];
        bb[l] = (const float*)d_in[7 + 5 * l];
    }

    const int NF = N_NODES * 128;
    unsigned short* YA  = (unsigned short*)d_ws;     // y ping
    unsigned short* YB  = YA + NF;                   // y pong
    unsigned short* H1  = YB + NF;                   // h1
    unsigned short* H2  = H1 + NF;                   // h2
    unsigned short* Wpk = H2 + NF;                   // 9 * 16384 packed weights
    int* deg = (int*)(Wpk + 9 * 16384);              // 50000
    unsigned short* csr16 = (unsigned short*)(deg + N_NODES); // 50000*64

    auto WH = [&](int i) { return Wpk + i * 16384; };
    // order: 0=Wp1 1=Ws1 2=Wn1 3=Wp2 4=Ws2 5=Wn2 6=Wp3 7=Ws3 8=Wn3

    WDescs wd;
    wd.W[0] = Wp[0]; wd.N[0] = 128;
    wd.W[1] = Ws[0]; wd.N[1] = 128;
    wd.W[2] = Wn[0]; wd.N[2] = 128;
    wd.W[3] = Wp[1]; wd.N[3] = 128;
    wd.W[4] = Ws[1]; wd.N[4] = 128;
    wd.W[5] = Wn[1]; wd.N[5] = 128;
    wd.W[6] = Wp[2]; wd.N[6] = 128;
    wd.W[7] = Ws[2]; wd.N[7] = 64;
    wd.W[8] = Wn[2]; wd.N[8] = 64;

    // 1) prep: pack weights + zero deg
    prep_kernel<<<576, 256, 0, stream>>>(wd, Wpk, deg);
    // 2) CSR fill + Y1 = relu(x@Wp1+bp1)
    mix_kernel<<<CSRB + GEMMB, 256, 0, stream>>>(esrc, edst, deg, csr16,
                                                 x, WH(0), bp[0], YA);
    // 3) layer 1: pool(YA) + dual(x, PL) -> h1, y2 -> YB
    pd_kernel<true, false><<<GEMMB, 256, 0, stream>>>(
        x, WH(1), WH(2), bb[0], YA, deg, csr16, H1, nullptr, WH(3), bp[1], YB);
    // 4) layer 2: pool(YB) + dual(h1, PL) -> h2, y3 -> YA
    pd_kernel<false, false><<<GEMMB, 256, 0, stream>>>(
        H1, WH(4), WH(5), bb[1], YB, deg, csr16, H2, nullptr, WH(6), bp[2], YA);
    // 5) layer 3: pool(YA) + dual(h2, PL) -> fp32 out
    pd_kernel<false, true><<<GEMMB, 256, 0, stream>>>(
        H2, WH(7), WH(8), bb[2], YA, deg, csr16, nullptr, (float*)d_out,
        nullptr, nullptr, nullptr);
}

// Round 10
// 349.833 us; speedup vs baseline: 1.1171x; 1.1171x over previous
//
#include <hip/hip_runtime.h>
#include <math.h>

#define N_NODES 50000
#define N_EDGES 800000
#define CAP 64                 // fixed CSR capacity/node (deg~Poisson(16))
#define RANGES 8
#define NODES_PER_RANGE 6250   // 50000 / 8
#define CSRB 1024              // csr blocks inside mix kernel
#define GEMMB 782              // ceil(50000/64)
#define LROW 136               // LDS row stride in shorts (272 B)

typedef __attribute__((ext_vector_type(8))) short short8;   // 8 bf16
typedef __attribute__((ext_vector_type(2))) short short2v;  // 2 bf16 packed
typedef __attribute__((ext_vector_type(4))) float f32x4;    // 4 fp32 acc

// ---------------- bf16 helpers (RNE) ----------------
__device__ __forceinline__ unsigned short f2bf(float f) {
    unsigned int u = __float_as_uint(f);
    return (unsigned short)((u + 0x7FFFu + ((u >> 16) & 1u)) >> 16);
}

// A fragment load: row-major fp32 (inline convert) or bf16.
template <bool F32>
__device__ __forceinline__ short8 loadA(const void* A, int off) {
    short8 r;
    if (F32) {
        const float* p = (const float*)A + off;   // 32B aligned
        float4 f0 = *(const float4*)p;
        float4 f1 = *(const float4*)(p + 4);
        r[0] = (short)f2bf(f0.x); r[1] = (short)f2bf(f0.y);
        r[2] = (short)f2bf(f0.z); r[3] = (short)f2bf(f0.w);
        r[4] = (short)f2bf(f1.x); r[5] = (short)f2bf(f1.y);
        r[6] = (short)f2bf(f1.z); r[7] = (short)f2bf(f1.w);
    } else {
        r = *(const short8*)((const unsigned short*)A + off);
    }
    return r;
}

// ---------------------------------------------------------------------------
// prep: pack 9 weight matrices fp32 -> bf16 fragment layout; zero deg.
// Bp[((c*N + n)*4 + q)*8 + j] = W[(c*32 + q*8 + j)*N + n].
// ---------------------------------------------------------------------------
struct WDescs { const float* W[9]; int N[9]; };

__global__ __launch_bounds__(256) void prep_kernel(
    WDescs wd, unsigned short* __restrict__ Wpk, int* __restrict__ deg)
{
    const int nthr = gridDim.x * 256;
    const int tid = blockIdx.x * 256 + threadIdx.x;
    for (int id = tid; id < 9 * 16384; id += nthr) {
        int mi = id >> 14;
        int loc = id & 16383;
        int N = wd.N[mi];
        if (loc < 128 * N) {
            int c = loc / (N * 32);
            int n = (loc - c * N * 32) >> 5;
            int k = c * 32 + (loc & 31);
            Wpk[mi * 16384 + loc] = f2bf(wd.W[mi][k * N + n]);
        }
    }
    for (int i = tid; i < N_NODES; i += nthr) deg[i] = 0;
}

// ---------------------------------------------------------------------------
// mix: blocks [0,CSRB) build CSR (XCD-range-partitioned, fixed capacity);
// blocks [CSRB, CSRB+GEMMB) compute Y1 = relu(x @ Wp1 + bp1) (bf16 out).
// Independent work -> no intra-kernel ordering needed.
// ---------------------------------------------------------------------------
__global__ __launch_bounds__(256) void mix_kernel(
    const int* __restrict__ esrc, const int* __restrict__ edst,
    int* __restrict__ deg, unsigned short* __restrict__ csr16,
    const float* __restrict__ x, const unsigned short* __restrict__ Wp1,
    const float* __restrict__ bp1, unsigned short* __restrict__ Y)
{
    if (blockIdx.x < CSRB) {
        int range = blockIdx.x & (RANGES - 1);
        for (int cb = blockIdx.x >> 3; cb < N_EDGES / 256; cb += CSRB / 8) {
            int e = cb * 256 + threadIdx.x;
            int d = edst[e];
            if ((unsigned)(d - range * NODES_PER_RANGE) < (unsigned)NODES_PER_RANGE) {
                int r = atomicAdd(&deg[d], 1);
                if (r < CAP) csr16[(d << 6) + r] = (unsigned short)esrc[e];
            }
        }
        return;
    }
    // ---- y-GEMM layer 1: Y1 = relu(x @ Wp1 + bp1) ----
    const int tile = blockIdx.x - CSRB;
    const int lane = threadIdx.x & 63;
    const int wv = threadIdx.x >> 6;
    const int cl = lane & 15;
    const int quad = lane >> 4;
    const int rowBase = tile * 64 + wv * 16;
    const int ar = min(rowBase + cl, N_NODES - 1);
    const int bLane = cl * 32 + quad * 8;

    f32x4 acc[8];
    #pragma unroll
    for (int t = 0; t < 8; ++t) acc[t] = (f32x4){0.f, 0.f, 0.f, 0.f};

    #pragma unroll
    for (int c = 0; c < 4; ++c) {
        short8 af = loadA<true>(x, ar * 128 + c * 32 + quad * 8);
        const unsigned short* Bc = Wp1 + c * 4096 + bLane;
        #pragma unroll
        for (int t = 0; t < 8; ++t) {
            short8 bf = *(const short8*)(Bc + t * 512);
            acc[t] = __builtin_amdgcn_mfma_f32_16x16x32_bf16(af, bf, acc[t], 0, 0, 0);
        }
    }
    const int row0 = rowBase + quad * 4;
    #pragma unroll
    for (int t = 0; t < 8; ++t) {
        float bc = bp1[t * 16 + cl];
        #pragma unroll
        for (int g = 0; g < 4; ++g) {
            int r = row0 + g;
            if (r < N_NODES)
                Y[r * 128 + t * 16 + cl] = f2bf(fmaxf(acc[t][g] + bc, 0.0f));
        }
    }
}

// ---------------------------------------------------------------------------
// pool: one wave per node (full 50k-wave parallelism — round-9 lesson: never
// couple this latency-bound gather to the GEMM tile grid). Gather max-pool
// over relu'd bf16 y (>=0 -> packed int16 max on raw bits); 8-deep index
// prefetch + 8 independent 256B row gathers in flight. acc=0 realizes
// zero-degree->0; bf16 max exact; deterministic.
// ---------------------------------------------------------------------------
__global__ __launch_bounds__(256) void pool_max8(
    const unsigned short* __restrict__ y, const int* __restrict__ deg,
    const unsigned short* __restrict__ csr16, unsigned short* __restrict__ pool)
{
    const int wv = threadIdx.x >> 6;
    const int d = threadIdx.x & 63;            // lane handles dims {2d, 2d+1}
    const int n = blockIdx.x * 4 + wv;
    const int e0 = n << 6;
    const int e1 = e0 + min(deg[n], CAP);
    const unsigned short* yb = y + 2 * d;

    short2v acc = (short2v){0, 0};             // +0.0 bf16 pair
    int e = e0;
    for (; e + 8 <= e1; e += 8) {
        int s0 = csr16[e + 0], s1 = csr16[e + 1];
        int s2 = csr16[e + 2], s3 = csr16[e + 3];
        int s4 = csr16[e + 4], s5 = csr16[e + 5];
        int s6 = csr16[e + 6], s7 = csr16[e + 7];
        short2v v0 = *(const short2v*)(yb + (s0 << 7));
        short2v v1 = *(const short2v*)(yb + (s1 << 7));
        short2v v2 = *(const short2v*)(yb + (s2 << 7));
        short2v v3 = *(const short2v*)(yb + (s3 << 7));
        short2v v4 = *(const short2v*)(yb + (s4 << 7));
        short2v v5 = *(const short2v*)(yb + (s5 << 7));
        short2v v6 = *(const short2v*)(yb + (s6 << 7));
        short2v v7 = *(const short2v*)(yb + (s7 << 7));
        acc = __builtin_elementwise_max(acc, v0);
        acc = __builtin_elementwise_max(acc, v1);
        acc = __builtin_elementwise_max(acc, v2);
        acc = __builtin_elementwise_max(acc, v3);
        acc = __builtin_elementwise_max(acc, v4);
        acc = __builtin_elementwise_max(acc, v5);
        acc = __builtin_elementwise_max(acc, v6);
        acc = __builtin_elementwise_max(acc, v7);
    }
    for (; e < e1; ++e) {
        int s = csr16[e];
        short2v v = *(const short2v*)(yb + (s << 7));
        acc = __builtin_elementwise_max(acc, v);
    }
    *(short2v*)(pool + n * 128 + 2 * d) = acc;
}

// ---------------------------------------------------------------------------
// dualy: dual-GEMM + l2norm + (next-layer y-GEMM | fp32 out).
// acc = A0 @ B0 + PL @ B1 (+bias) -> l2norm+relu -> h. For non-LAST, h is
// staged through this wave's private LDS region (C-layout -> A-layout round
// trip, no __syncthreads: same-wave DS ops are in-order) and a second MFMA
// pass computes Yout = relu(h @ Bnext + bnext).
//   A0F32: A-seg0 is fp32 (layer 1, A0 = x) else bf16.
//   LAST:  N=64, fp32 out, no y-GEMM.
// ---------------------------------------------------------------------------
template <bool A0F32, bool LAST>
__global__ __launch_bounds__(256) void dualy_kernel(
    const void* __restrict__ A0,
    const unsigned short* __restrict__ B0, const unsigned short* __restrict__ B1,
    const float* __restrict__ bias,
    const unsigned short* __restrict__ PL,
    unsigned short* __restrict__ outH, float* __restrict__ outF,
    const unsigned short* __restrict__ Bnext, const float* __restrict__ bnext,
    unsigned short* __restrict__ Yout)
{
    constexpr int NT = LAST ? 4 : 8;
    constexpr int N = NT * 16;
    __shared__ unsigned short lds[4][16 * LROW];   // 17.4 KB (h staging)

    const int lane = threadIdx.x & 63;
    const int wv = threadIdx.x >> 6;
    const int cl = lane & 15;
    const int quad = lane >> 4;
    const int nodeBase = blockIdx.x * 64 + wv * 16;
    unsigned short* plw = &lds[wv][0];

    const int ar = min(nodeBase + cl, N_NODES - 1);
    const int aBase = ar * 128 + quad * 8;
    const int bLane = cl * 32 + quad * 8;

    f32x4 acc[NT];
    #pragma unroll
    for (int t = 0; t < NT; ++t) acc[t] = (f32x4){0.f, 0.f, 0.f, 0.f};

    #pragma unroll
    for (int c = 0; c < 4; ++c) {
        short8 a0 = loadA<A0F32>(A0, aBase + c * 32);
        short8 a1 = *(const short8*)(PL + aBase + c * 32);
        const unsigned short* B0c = B0 + c * (N * 32) + bLane;
        const unsigned short* B1c = B1 + c * (N * 32) + bLane;
        #pragma unroll
        for (int t = 0; t < NT; ++t) {
            short8 bf = *(const short8*)(B0c + t * 512);
            acc[t] = __builtin_amdgcn_mfma_f32_16x16x32_bf16(a0, bf, acc[t], 0, 0, 0);
        }
        #pragma unroll
        for (int t = 0; t < NT; ++t) {
            short8 bf = *(const short8*)(B1c + t * 512);
            acc[t] = __builtin_amdgcn_mfma_f32_16x16x32_bf16(a1, bf, acc[t], 0, 0, 0);
        }
    }

    #pragma unroll
    for (int t = 0; t < NT; ++t) {
        float bc = bias[t * 16 + cl];
        #pragma unroll
        for (int g = 0; g < 4; ++g) acc[t][g] += bc;
    }

    // ---- fused row-wise L2 norm (row lives in 16 lanes of this quad group) ----
    float inv[4];
    #pragma unroll
    for (int g = 0; g < 4; ++g) {
        float s = 0.f;
        #pragma unroll
        for (int t = 0; t < NT; ++t) s += acc[t][g] * acc[t][g];
        s += __shfl_xor(s, 1, 64);
        s += __shfl_xor(s, 2, 64);
        s += __shfl_xor(s, 4, 64);
        s += __shfl_xor(s, 8, 64);
        inv[g] = 1.0f / fmaxf(sqrtf(s), 1e-12f);
    }

    const int row0 = nodeBase + quad * 4;

    if (LAST) {
        #pragma unroll
        for (int t = 0; t < NT; ++t)
            #pragma unroll
            for (int g = 0; g < 4; ++g) {
                int r = row0 + g;
                if (r < N_NODES)
                    outF[r * N + t * 16 + cl] = fmaxf(acc[t][g] * inv[g], 0.0f);
            }
        return;
    }

    // h -> global (next dualy's A0) + LDS stage (C-layout -> A-layout)
    #pragma unroll
    for (int t = 0; t < NT; ++t)
        #pragma unroll
        for (int g = 0; g < 4; ++g) {
            int r = row0 + g;
            unsigned short h = f2bf(fmaxf(acc[t][g] * inv[g], 0.0f));
            if (r < N_NODES) outH[r * 128 + t * 16 + cl] = h;
            plw[(quad * 4 + g) * LROW + t * 16 + cl] = h;
        }

    // ---- y-GEMM for the next layer: Yout = relu(h @ Bnext + bnext) ----
    f32x4 ya[8];
    #pragma unroll
    for (int t = 0; t < 8; ++t) ya[t] = (f32x4){0.f, 0.f, 0.f, 0.f};
    #pragma unroll
    for (int c = 0; c < 4; ++c) {
        short8 af = *(const short8*)(plw + cl * LROW + c * 32 + quad * 8);
        const unsigned short* Bc = Bnext + c * 4096 + bLane;
        #pragma unroll
        for (int t = 0; t < 8; ++t) {
            short8 bf = *(const short8*)(Bc + t * 512);
            ya[t] = __builtin_amdgcn_mfma_f32_16x16x32_bf16(af, bf, ya[t], 0, 0, 0);
        }
    }
    #pragma unroll
    for (int t = 0; t < 8; ++t) {
        float bc = bnext[t * 16 + cl];
        #pragma unroll
        for (int g = 0; g < 4; ++g) {
            int r = row0 + g;
            if (r < N_NODES)
                Yout[r * 128 + t * 16 + cl] = f2bf(fmaxf(ya[t][g] + bc, 0.0f));
        }
    }
}

extern "C" void kernel_launch(void* const* d_in, const int* in_sizes, int n_in,
                              void* d_out, int out_size, void* d_ws, size_t ws_size,
                              hipStream_t stream) {
    const float* x    = (const float*)d_in[0];
    const int*   esrc = (const int*)d_in[1];
    const int*   edst = (const int*)d_in[2];
    const float* Wp[3], *bp[3], *Ws[3], *Wn[3], *bb[3];
    for (int l = 0; l < 3; ++l) {
        Wp[l] = (const float*)d_in[3 + 5 * l];
        bp[l] = (const float*)d_in[4 + 5 * l];
        Ws[l] = (const float*)d_in[5 + 5 * l];
        Wn[l] = (const float*)d_in[6 + 5 * l];
        bb[l] = (const float*)d_in[7 + 5 * l];
    }

    const int NF = N_NODES * 128;
    unsigned short* YA  = (unsigned short*)d_ws;     // y ping
    unsigned short* YB  = YA + NF;                   // y pong
    unsigned short* PL  = YB + NF;                   // pool
    unsigned short* H1  = PL + NF;                   // h1
    unsigned short* H2  = H1 + NF;                   // h2
    unsigned short* Wpk = H2 + NF;                   // 9 * 16384 packed weights
    int* deg = (int*)(Wpk + 9 * 16384);              // 50000
    unsigned short* csr16 = (unsigned short*)(deg + N_NODES); // 50000*64

    auto WH = [&](int i) { return Wpk + i * 16384; };
    // order: 0=Wp1 1=Ws1 2=Wn1 3=Wp2 4=Ws2 5=Wn2 6=Wp3 7=Ws3 8=Wn3

    WDescs wd;
    wd.W[0] = Wp[0]; wd.N[0] = 128;
    wd.W[1] = Ws[0]; wd.N[1] = 128;
    wd.W[2] = Wn[0]; wd.N[2] = 128;
    wd.W[3] = Wp[1]; wd.N[3] = 128;
    wd.W[4] = Ws[1]; wd.N[4] = 128;
    wd.W[5] = Wn[1]; wd.N[5] = 128;
    wd.W[6] = Wp[2]; wd.N[6] = 128;
    wd.W[7] = Ws[2]; wd.N[7] = 64;
    wd.W[8] = Wn[2]; wd.N[8] = 64;

    const int poolBlocks = N_NODES / 4;   // 12500

    // 1) prep: pack weights + zero deg
    prep_kernel<<<576, 256, 0, stream>>>(wd, Wpk, deg);
    // 2) CSR fill + Y1 = relu(x@Wp1+bp1)
    mix_kernel<<<CSRB + GEMMB, 256, 0, stream>>>(esrc, edst, deg, csr16,
                                                 x, WH(0), bp[0], YA);
    // 3) layer 1
    pool_max8<<<poolBlocks, 256, 0, stream>>>(YA, deg, csr16, PL);
    dualy_kernel<true, false><<<GEMMB, 256, 0, stream>>>(
        x, WH(1), WH(2), bb[0], PL, H1, nullptr, WH(3), bp[1], YB);
    // 4) layer 2
    pool_max8<<<poolBlocks, 256, 0, stream>>>(YB, deg, csr16, PL);
    dualy_kernel<false, false><<<GEMMB, 256, 0, stream>>>(
        H1, WH(4), WH(5), bb[1], PL, H2, nullptr, WH(6), bp[2], YA);
    // 5) layer 3
    pool_max8<<<poolBlocks, 256, 0, stream>>>(YA, deg, csr16, PL);
    dualy_kernel<false, true><<<GEMMB, 256, 0, stream>>>(
        H2, WH(7), WH(8), bb[2], PL, nullptr, (float*)d_out,
        nullptr, nullptr, nullptr);
}

// Round 11
// 348.932 us; speedup vs baseline: 1.1200x; 1.0026x over previous
//
#include <hip/hip_runtime.h>
#include <math.h>

#define N_NODES 50000
#define N_EDGES 800000
#define CAP 64                 // fixed CSR capacity/node (deg~Poisson(16))
#define RANGES 8
#define NODES_PER_RANGE 6250   // 50000 / 8
#define GEMMB 782              // ceil(50000/64)
#define CSRB (N_EDGES / 256 * RANGES)   // 25000 one-shot csr blocks
#define LROW 136               // LDS row stride in shorts (272 B)

typedef __attribute__((ext_vector_type(8))) short short8;   // 8 bf16
typedef __attribute__((ext_vector_type(4))) short short4v;  // 4 bf16 packed
typedef __attribute__((ext_vector_type(4))) float f32x4;    // 4 fp32 acc

// ---------------- bf16 helpers (RNE) ----------------
__device__ __forceinline__ unsigned short f2bf(float f) {
    unsigned int u = __float_as_uint(f);
    return (unsigned short)((u + 0x7FFFu + ((u >> 16) & 1u)) >> 16);
}

// A fragment load: row-major fp32 (inline convert) or bf16.
template <bool F32>
__device__ __forceinline__ short8 loadA(const void* A, int off) {
    short8 r;
    if (F32) {
        const float* p = (const float*)A + off;   // 32B aligned
        float4 f0 = *(const float4*)p;
        float4 f1 = *(const float4*)(p + 4);
        r[0] = (short)f2bf(f0.x); r[1] = (short)f2bf(f0.y);
        r[2] = (short)f2bf(f0.z); r[3] = (short)f2bf(f0.w);
        r[4] = (short)f2bf(f1.x); r[5] = (short)f2bf(f1.y);
        r[6] = (short)f2bf(f1.z); r[7] = (short)f2bf(f1.w);
    } else {
        r = *(const short8*)((const unsigned short*)A + off);
    }
    return r;
}

// ---------------------------------------------------------------------------
// prep: pack 9 weight matrices fp32 -> bf16 fragment layout; zero deg.
// Bp[((c*N + n)*4 + q)*8 + j] = W[(c*32 + q*8 + j)*N + n].
// ---------------------------------------------------------------------------
struct WDescs { const float* W[9]; int N[9]; };

__global__ __launch_bounds__(256) void prep_kernel(
    WDescs wd, unsigned short* __restrict__ Wpk, int* __restrict__ deg)
{
    const int nthr = gridDim.x * 256;
    const int tid = blockIdx.x * 256 + threadIdx.x;
    for (int id = tid; id < 9 * 16384; id += nthr) {
        int mi = id >> 14;
        int loc = id & 16383;
        int N = wd.N[mi];
        if (loc < 128 * N) {
            int c = loc / (N * 32);
            int n = (loc - c * N * 32) >> 5;
            int k = c * 32 + (loc & 31);
            Wpk[mi * 16384 + loc] = f2bf(wd.W[mi][k * N + n]);
        }
    }
    for (int i = tid; i < N_NODES; i += nthr) deg[i] = 0;
}

// ---------------------------------------------------------------------------
// mix: blocks [0,GEMMB) compute Y1 = relu(x @ Wp1 + bp1); blocks
// [GEMMB, GEMMB+CSRB) build CSR — ONE edge chunk per block, no loop
// (round-10 lesson: the 1024-block looped version serialized the atomic
// latency; one-shot blocks hide it with TLP, as in round 7). GEMM blocks
// first so the long-pole tiles launch early.
// ---------------------------------------------------------------------------
__global__ __launch_bounds__(256) void mix_kernel(
    const int* __restrict__ esrc, const int* __restrict__ edst,
    int* __restrict__ deg, unsigned short* __restrict__ csr16,
    const float* __restrict__ x, const unsigned short* __restrict__ Wp1,
    const float* __restrict__ bp1, unsigned short* __restrict__ Y)
{
    if (blockIdx.x >= GEMMB) {
        int b = blockIdx.x - GEMMB;
        int range = b & (RANGES - 1);
        int e = (b >> 3) * 256 + threadIdx.x;       // grid exact per range
        int d = edst[e];
        if ((unsigned)(d - range * NODES_PER_RANGE) < (unsigned)NODES_PER_RANGE) {
            int r = atomicAdd(&deg[d], 1);
            if (r < CAP) csr16[(d << 6) + r] = (unsigned short)esrc[e];
        }
        return;
    }
    // ---- y-GEMM layer 1: Y1 = relu(x @ Wp1 + bp1) ----
    const int tile = blockIdx.x;
    const int lane = threadIdx.x & 63;
    const int wv = threadIdx.x >> 6;
    const int cl = lane & 15;
    const int quad = lane >> 4;
    const int rowBase = tile * 64 + wv * 16;
    const int ar = min(rowBase + cl, N_NODES - 1);
    const int bLane = cl * 32 + quad * 8;

    f32x4 acc[8];
    #pragma unroll
    for (int t = 0; t < 8; ++t) acc[t] = (f32x4){0.f, 0.f, 0.f, 0.f};

    #pragma unroll
    for (int c = 0; c < 4; ++c) {
        short8 af = loadA<true>(x, ar * 128 + c * 32 + quad * 8);
        const unsigned short* Bc = Wp1 + c * 4096 + bLane;
        #pragma unroll
        for (int t = 0; t < 8; ++t) {
            short8 bf = *(const short8*)(Bc + t * 512);
            acc[t] = __builtin_amdgcn_mfma_f32_16x16x32_bf16(af, bf, acc[t], 0, 0, 0);
        }
    }
    const int row0 = rowBase + quad * 4;
    #pragma unroll
    for (int t = 0; t < 8; ++t) {
        float bc = bp1[t * 16 + cl];
        #pragma unroll
        for (int g = 0; g < 4; ++g) {
            int r = row0 + g;
            if (r < N_NODES)
                Y[r * 128 + t * 16 + cl] = f2bf(fmaxf(acc[t][g] + bc, 0.0f));
        }
    }
}

// ---------------------------------------------------------------------------
// pool: one wave per node (full 50k-wave parallelism). Lane-half edge
// pairing: lanes 0-31 take even-slot edges, 32-63 odd-slot; each lane loads
// short4 (8B) so ONE load instruction fetches two 256B rows. Indices arrive
// as one uint2 broadcast per half per 8 edges. Per 8 edges: 1 idx load +
// 4 row loads + 8 pk_max (vs 8+8+8 before). relu'd bf16 >= 0 -> packed
// int16 max on raw bits is exact fp max; acc=0 realizes zero-degree->0.
// ---------------------------------------------------------------------------
__global__ __launch_bounds__(256) void pool_max4(
    const unsigned short* __restrict__ y, const int* __restrict__ deg,
    const unsigned short* __restrict__ csr16, unsigned short* __restrict__ pool)
{
    const int wv = threadIdx.x >> 6;
    const int lane = threadIdx.x & 63;
    const int half = lane >> 5;          // which edge of the pair
    const int q = lane & 31;             // dim quad: dims [4q, 4q+4)
    const int n = blockIdx.x * 4 + wv;
    const int e0 = n << 6;
    const int e1 = e0 + min(deg[n], CAP);
    const unsigned short* yb = y + 4 * q;

    short4v acc = (short4v){0, 0, 0, 0};       // +0.0 bf16 quad
    int e = e0;
    for (; e + 8 <= e1; e += 8) {
        // this half's 4 indices: slots e+4*half .. e+4*half+3 (8B broadcast)
        uint2 I = *(const uint2*)(csr16 + e + (half << 2));
        int sa = (int)(I.x & 0xFFFF), sb = (int)(I.x >> 16);
        int sc = (int)(I.y & 0xFFFF), sd = (int)(I.y >> 16);
        short4v va = *(const short4v*)(yb + (sa << 7));
        short4v vb = *(const short4v*)(yb + (sb << 7));
        short4v vc = *(const short4v*)(yb + (sc << 7));
        short4v vd = *(const short4v*)(yb + (sd << 7));
        acc = __builtin_elementwise_max(acc, va);
        acc = __builtin_elementwise_max(acc, vb);
        acc = __builtin_elementwise_max(acc, vc);
        acc = __builtin_elementwise_max(acc, vd);
    }
    for (; e < e1; ++e) {                      // tail: both halves duplicate
        int s = csr16[e];
        short4v v = *(const short4v*)(yb + (s << 7));
        acc = __builtin_elementwise_max(acc, v);
    }
    // merge the two halves (lanes q and q+32 hold the same dims)
    int2 ai = *(int2*)&acc;
    int2 bi;
    bi.x = __shfl_xor(ai.x, 32, 64);
    bi.y = __shfl_xor(ai.y, 32, 64);
    short4v other = *(short4v*)&bi;
    acc = __builtin_elementwise_max(acc, other);
    if (half == 0)
        *(short4v*)(pool + n * 128 + 4 * q) = acc;
}

// ---------------------------------------------------------------------------
// dualy: dual-GEMM + l2norm + (next-layer y-GEMM | fp32 out).
// acc = A0 @ B0 + PL @ B1 (+bias) -> l2norm+relu -> h. For non-LAST, h is
// staged through this wave's private LDS region (C-layout -> A-layout round
// trip, no __syncthreads: same-wave DS ops are in-order) and a second MFMA
// pass computes Yout = relu(h @ Bnext + bnext).
// ---------------------------------------------------------------------------
template <bool A0F32, bool LAST>
__global__ __launch_bounds__(256) void dualy_kernel(
    const void* __restrict__ A0,
    const unsigned short* __restrict__ B0, const unsigned short* __restrict__ B1,
    const float* __restrict__ bias,
    const unsigned short* __restrict__ PL,
    unsigned short* __restrict__ outH, float* __restrict__ outF,
    const unsigned short* __restrict__ Bnext, const float* __restrict__ bnext,
    unsigned short* __restrict__ Yout)
{
    constexpr int NT = LAST ? 4 : 8;
    constexpr int N = NT * 16;
    __shared__ unsigned short lds[4][16 * LROW];   // 17.4 KB (h staging)

    const int lane = threadIdx.x & 63;
    const int wv = threadIdx.x >> 6;
    const int cl = lane & 15;
    const int quad = lane >> 4;
    const int nodeBase = blockIdx.x * 64 + wv * 16;
    unsigned short* plw = &lds[wv][0];

    const int ar = min(nodeBase + cl, N_NODES - 1);
    const int aBase = ar * 128 + quad * 8;
    const int bLane = cl * 32 + quad * 8;

    f32x4 acc[NT];
    #pragma unroll
    for (int t = 0; t < NT; ++t) acc[t] = (f32x4){0.f, 0.f, 0.f, 0.f};

    #pragma unroll
    for (int c = 0; c < 4; ++c) {
        short8 a0 = loadA<A0F32>(A0, aBase + c * 32);
        short8 a1 = *(const short8*)(PL + aBase + c * 32);
        const unsigned short* B0c = B0 + c * (N * 32) + bLane;
        const unsigned short* B1c = B1 + c * (N * 32) + bLane;
        #pragma unroll
        for (int t = 0; t < NT; ++t) {
            short8 bf = *(const short8*)(B0c + t * 512);
            acc[t] = __builtin_amdgcn_mfma_f32_16x16x32_bf16(a0, bf, acc[t], 0, 0, 0);
        }
        #pragma unroll
        for (int t = 0; t < NT; ++t) {
            short8 bf = *(const short8*)(B1c + t * 512);
            acc[t] = __builtin_amdgcn_mfma_f32_16x16x32_bf16(a1, bf, acc[t], 0, 0, 0);
        }
    }

    #pragma unroll
    for (int t = 0; t < NT; ++t) {
        float bc = bias[t * 16 + cl];
        #pragma unroll
        for (int g = 0; g < 4; ++g) acc[t][g] += bc;
    }

    // ---- fused row-wise L2 norm (row lives in 16 lanes of this quad group) ----
    float inv[4];
    #pragma unroll
    for (int g = 0; g < 4; ++g) {
        float s = 0.f;
        #pragma unroll
        for (int t = 0; t < NT; ++t) s += acc[t][g] * acc[t][g];
        s += __shfl_xor(s, 1, 64);
        s += __shfl_xor(s, 2, 64);
        s += __shfl_xor(s, 4, 64);
        s += __shfl_xor(s, 8, 64);
        inv[g] = 1.0f / fmaxf(sqrtf(s), 1e-12f);
    }

    const int row0 = nodeBase + quad * 4;

    if (LAST) {
        #pragma unroll
        for (int t = 0; t < NT; ++t)
            #pragma unroll
            for (int g = 0; g < 4; ++g) {
                int r = row0 + g;
                if (r < N_NODES)
                    outF[r * N + t * 16 + cl] = fmaxf(acc[t][g] * inv[g], 0.0f);
            }
        return;
    }

    // h -> global (next dualy's A0) + LDS stage (C-layout -> A-layout)
    #pragma unroll
    for (int t = 0; t < NT; ++t)
        #pragma unroll
        for (int g = 0; g < 4; ++g) {
            int r = row0 + g;
            unsigned short h = f2bf(fmaxf(acc[t][g] * inv[g], 0.0f));
            if (r < N_NODES) outH[r * 128 + t * 16 + cl] = h;
            plw[(quad * 4 + g) * LROW + t * 16 + cl] = h;
        }

    // ---- y-GEMM for the next layer: Yout = relu(h @ Bnext + bnext) ----
    f32x4 ya[8];
    #pragma unroll
    for (int t = 0; t < 8; ++t) ya[t] = (f32x4){0.f, 0.f, 0.f, 0.f};
    #pragma unroll
    for (int c = 0; c < 4; ++c) {
        short8 af = *(const short8*)(plw + cl * LROW + c * 32 + quad * 8);
        const unsigned short* Bc = Bnext + c * 4096 + bLane;
        #pragma unroll
        for (int t = 0; t < 8; ++t) {
            short8 bf = *(const short8*)(Bc + t * 512);
            ya[t] = __builtin_amdgcn_mfma_f32_16x16x32_bf16(af, bf, ya[t], 0, 0, 0);
        }
    }
    #pragma unroll
    for (int t = 0; t < 8; ++t) {
        float bc = bnext[t * 16 + cl];
        #pragma unroll
        for (int g = 0; g < 4; ++g) {
            int r = row0 + g;
            if (r < N_NODES)
                Yout[r * 128 + t * 16 + cl] = f2bf(fmaxf(ya[t][g] + bc, 0.0f));
        }
    }
}

extern "C" void kernel_launch(void* const* d_in, const int* in_sizes, int n_in,
                              void* d_out, int out_size, void* d_ws, size_t ws_size,
                              hipStream_t stream) {
    const float* x    = (const float*)d_in[0];
    const int*   esrc = (const int*)d_in[1];
    const int*   edst = (const int*)d_in[2];
    const float* Wp[3], *bp[3], *Ws[3], *Wn[3], *bb[3];
    for (int l = 0; l < 3; ++l) {
        Wp[l] = (const float*)d_in[3 + 5 * l];
        bp[l] = (const float*)d_in[4 + 5 * l];
        Ws[l] = (const float*)d_in[5 + 5 * l];
        Wn[l] = (const float*)d_in[6 + 5 * l];
        bb[l] = (const float*)d_in[7 + 5 * l];
    }

    const int NF = N_NODES * 128;
    unsigned short* YA  = (unsigned short*)d_ws;     // y ping
    unsigned short* YB  = YA + NF;                   // y pong
    unsigned short* PL  = YB + NF;                   // pool
    unsigned short* H1  = PL + NF;                   // h1
    unsigned short* H2  = H1 + NF;                   // h2
    unsigned short* Wpk = H2 + NF;                   // 9 * 16384 packed weights
    int* deg = (int*)(Wpk + 9 * 16384);              // 50000
    unsigned short* csr16 = (unsigned short*)(deg + N_NODES); // 50000*64

    auto WH = [&](int i) { return Wpk + i * 16384; };
    // order: 0=Wp1 1=Ws1 2=Wn1 3=Wp2 4=Ws2 5=Wn2 6=Wp3 7=Ws3 8=Wn3

    WDescs wd;
    wd.W[0] = Wp[0]; wd.N[0] = 128;
    wd.W[1] = Ws[0]; wd.N[1] = 128;
    wd.W[2] = Wn[0]; wd.N[2] = 128;
    wd.W[3] = Wp[1]; wd.N[3] = 128;
    wd.W[4] = Ws[1]; wd.N[4] = 128;
    wd.W[5] = Wn[1]; wd.N[5] = 128;
    wd.W[6] = Wp[2]; wd.N[6] = 128;
    wd.W[7] = Ws[2]; wd.N[7] = 64;
    wd.W[8] = Wn[2]; wd.N[8] = 64;

    const int poolBlocks = N_NODES / 4;   // 12500

    // 1) prep: pack weights + zero deg
    prep_kernel<<<576, 256, 0, stream>>>(wd, Wpk, deg);
    // 2) Y1 = relu(x@Wp1+bp1) (blocks 0..781) + one-shot CSR fill (rest)
    mix_kernel<<<GEMMB + CSRB, 256, 0, stream>>>(esrc, edst, deg, csr16,
                                                 x, WH(0), bp[0], YA);
    // 3) layer 1
    pool_max4<<<poolBlocks, 256, 0, stream>>>(YA, deg, csr16, PL);
    dualy_kernel<true, false><<<GEMMB, 256, 0, stream>>>(
        x, WH(1), WH(2), bb[0], PL, H1, nullptr, WH(3), bp[1], YB);
    // 4) layer 2
    pool_max4<<<poolBlocks, 256, 0, stream>>>(YB, deg, csr16, PL);
    dualy_kernel<false, false><<<GEMMB, 256, 0, stream>>>(
        H1, WH(4), WH(5), bb[1], PL, H2, nullptr, WH(6), bp[2], YA);
    // 5) layer 3
    pool_max4<<<poolBlocks, 256, 0, stream>>>(YA, deg, csr16, PL);
    dualy_kernel<false, true><<<GEMMB, 256, 0, stream>>>(
        H2, WH(7), WH(8), bb[2], PL, nullptr, (float*)d_out,
        nullptr, nullptr, nullptr);
}